// Round 11
// baseline (365.566 us; speedup 1.0000x reference)
//
#include <hip/hip_runtime.h>
#include <hip/hip_bf16.h>

#define TT 4096
#define BB 32

typedef unsigned short ushort_t;
typedef __attribute__((ext_vector_type(8))) short short8v;
typedef __attribute__((ext_vector_type(4))) float float4v;

__device__ inline ushort_t bf16rn(float v) {
    unsigned u = __float_as_uint(v);
    unsigned r = (u + 0x7FFFu + ((u >> 16) & 1u)) >> 16;
    return (ushort_t)r;
}
__device__ inline float bf16tof(ushort_t h) {
    return __uint_as_float(((unsigned)h) << 16);
}
__device__ inline int SW(int i) { return i + (i >> 5); }

__device__ inline float fast_tanh(float x) {
    float e = __builtin_amdgcn_exp2f(x * 2.8853900817779268f);
    return 1.0f - 2.0f * __builtin_amdgcn_rcpf(e + 1.0f);
}
__device__ inline float fast_sin(float x) {
    return __builtin_amdgcn_sinf(x * 0.15915494309189535f);
}

// ---------------- K1: expm(hams*DT) via Taylor ------------------------------
__global__ __launch_bounds__(256) void k1_expm(const float* __restrict__ hams,
                                               float* __restrict__ U)
{
    int c = blockIdx.x, tid = threadIdx.x;
    __shared__ float M[4096], P[4096], Acc[4096];
    const float* H = hams + c * 4096;
    for (int k = tid; k < 4096; k += 256) {
        float m = H[k] * 0.1f;
        M[k] = m; P[k] = m;
        Acc[k] = m + (((k >> 6) == (k & 63)) ? 1.0f : 0.0f);
    }
    __syncthreads();
    int j = tid & 63;
    float mcol[64];
    #pragma unroll
    for (int k = 0; k < 64; k++) mcol[k] = M[k * 64 + j];
    for (int term = 2; term <= 8; term++) {
        float inv = 1.0f / (float)term;
        float np_[16];
        #pragma unroll
        for (int r = 0; r < 16; r++) {
            int i = (tid >> 6) + 4 * r;
            float a = 0.f;
            #pragma unroll
            for (int k = 0; k < 64; k++) a = fmaf(P[i * 64 + k], mcol[k], a);
            np_[r] = a * inv;
        }
        __syncthreads();
        #pragma unroll
        for (int r = 0; r < 16; r++) {
            int i = (tid >> 6) + 4 * r;
            P[i * 64 + j] = np_[r];
            Acc[i * 64 + j] += np_[r];
        }
        __syncthreads();
    }
    for (int k = tid; k < 4096; k += 256) U[c * 4096 + k] = Acc[k];
}

// ---------------- all weight f32 -> bf16 hi/lo planes -----------------------
__global__ void split_all(const float* __restrict__ pw2, const float* __restrict__ wcw,
                          const float* __restrict__ qw1, const float* __restrict__ qw2,
                          ushort_t* __restrict__ wb)
{
    int i = blockIdx.x * 256 + threadIdx.x;
    const float* src; ushort_t *hi, *lo; int off;
    if (i < 32768)      { src = pw2; hi = wb;          lo = wb + 32768;  off = i; }
    else if (i < 40960) { src = wcw; hi = wb + 65536;  lo = wb + 73728;  off = i - 32768; }
    else if (i < 49152) { src = qw1; hi = wb + 81920;  lo = wb + 90112;  off = i - 40960; }
    else                { src = qw2; hi = wb + 98304;  lo = wb + 131072; off = i - 49152; }
    float v = src[off];
    ushort_t h = bf16rn(v);
    hi[off] = h;
    lo[off] = bf16rn(v - bf16tof(h));
}

// ---------------- stage1: x -> wcf (single bf16 plane, coalesced store) -----
__global__ __launch_bounds__(256, 2) void gemm_s1(
    const ushort_t* __restrict__ Whi, const ushort_t* __restrict__ Wlo,
    const float* __restrict__ bias,
    const float* __restrict__ x, const float* __restrict__ pw1,
    const float* __restrict__ pb1,
    const float* __restrict__ freq, const float* __restrict__ ampc,
    ushort_t* __restrict__ O)
{
    __shared__ ushort_t OT[2][2048];
    int tid = threadIdx.x;
    int w = tid >> 6, l = tid & 63, l15 = l & 15, kg = l >> 4;
    int kofb = kg * 8;

    short8v bh[4][4], bl[4][4];
    #pragma unroll
    for (int i = 0; i < 4; i++) {
        int n = (w + 4 * i) * 16 + l15;
        #pragma unroll
        for (int kc = 0; kc < 4; kc++) {
            int kof = kc * 32 + kofb;
            bh[i][kc] = *(const short8v*)(Whi + (size_t)n * 128 + kof);
            bl[i][kc] = *(const short8v*)(Wlo + (size_t)n * 128 + kof);
        }
    }
    float am = ampc[0];
    float fr[2], ba[2], bp[2];
    #pragma unroll
    for (int i = 0; i < 2; i++) {
        int f = (w + 4 * i) * 16 + l15;
        fr[i] = freq[f]; ba[i] = bias[f]; bp[i] = bias[128 + f];
    }

    int mbase = blockIdx.x * 64;
    for (int mi = 0; mi < 4; mi++) {
        int m0 = mbase + mi * 16;
        float xv = x[m0 + l15];
        short8v ah[4], al[4];
        #pragma unroll
        for (int kc = 0; kc < 4; kc++) {
            int k0 = kc * 32 + kofb;
            float4 w0 = *(const float4*)(pw1 + k0);
            float4 w1v = *(const float4*)(pw1 + k0 + 4);
            float4 b0 = *(const float4*)(pb1 + k0);
            float4 b1v = *(const float4*)(pb1 + k0 + 4);
            #pragma unroll
            for (int j = 0; j < 8; j++) {
                float wj = (j < 4) ? (&w0.x)[j] : (&w1v.x)[j - 4];
                float bj = (j < 4) ? (&b0.x)[j] : (&b1v.x)[j - 4];
                float v = fast_tanh(fmaf(xv, wj, bj));
                ushort_t h = bf16rn(v);
                ah[kc][j] = (short)h;
                al[kc][j] = (short)bf16rn(v - bf16tof(h));
            }
        }
        float4v acc[4];
        #pragma unroll
        for (int i = 0; i < 4; i++) acc[i] = (float4v){0.f, 0.f, 0.f, 0.f};
        #pragma unroll
        for (int kc = 0; kc < 4; kc++) {
            #pragma unroll
            for (int i = 0; i < 4; i++) {
                acc[i] = __builtin_amdgcn_mfma_f32_16x16x32_bf16(ah[kc], bh[i][kc], acc[i], 0, 0, 0);
                acc[i] = __builtin_amdgcn_mfma_f32_16x16x32_bf16(ah[kc], bl[i][kc], acc[i], 0, 0, 0);
                acc[i] = __builtin_amdgcn_mfma_f32_16x16x32_bf16(al[kc], bh[i][kc], acc[i], 0, 0, 0);
            }
        }
        int buf = mi & 1;
        #pragma unroll
        for (int i = 0; i < 2; i++) {
            int f = (w + 4 * i) * 16 + l15;
            #pragma unroll
            for (int r = 0; r < 4; r++) {
                int m = m0 + kg * 4 + r;
                float timev = 6.283185307179586f * (float)(m & 4095) / 4095.0f;
                float a = fast_tanh(acc[i][r] + ba[i]) * am;
                float ph = acc[i + 2][r] + bp[i];
                float v = a * fast_sin(fmaf(fr[i], timev, ph));
                OT[buf][(kg * 4 + r) * 128 + f] = bf16rn(v);
            }
        }
        __syncthreads();
        *(uint4*)(O + (size_t)m0 * 128 + tid * 8) = *(const uint4*)(&OT[buf][tid * 8]);
    }
}

// ---------------- s23: wcf(bf16) -> wf -> q1 (hi/lo, coalesced stores) ------
__global__ __launch_bounds__(256, 2) void s23_v2(
    const ushort_t* __restrict__ A,                                      // wcf
    const ushort_t* __restrict__ W2hi, const ushort_t* __restrict__ W2lo,
    const float* __restrict__ b2,
    const ushort_t* __restrict__ W3hi, const ushort_t* __restrict__ W3lo,
    const float* __restrict__ b3,
    ushort_t* __restrict__ OHi, ushort_t* __restrict__ OLo)
{
    __shared__ unsigned WF[2][16][65];
    __shared__ ushort_t OThi[2][2048], OTlo[2][2048];
    int tid = threadIdx.x;
    int w = tid >> 6, l = tid & 63, l15 = l & 15, kg = l >> 4;
    int kofb = kg * 8;

    short8v w2h[4], w2l[4];
    #pragma unroll
    for (int kc = 0; kc < 4; kc++) {
        int n = w * 16 + l15;
        int kof = kc * 32 + kofb;
        w2h[kc] = *(const short8v*)(W2hi + (size_t)n * 128 + kof);
        w2l[kc] = *(const short8v*)(W2lo + (size_t)n * 128 + kof);
    }
    short8v w3h[2][2], w3l[2][2];
    #pragma unroll
    for (int i = 0; i < 2; i++) {
        int n = (w + 4 * i) * 16 + l15;
        #pragma unroll
        for (int kc = 0; kc < 2; kc++) {
            int kof = kc * 32 + kofb;
            w3h[i][kc] = *(const short8v*)(W3hi + (size_t)n * 64 + kof);
            w3l[i][kc] = *(const short8v*)(W3lo + (size_t)n * 64 + kof);
        }
    }
    float b2v = b2[w * 16 + l15];
    float b3v[2];
    #pragma unroll
    for (int i = 0; i < 2; i++) b3v[i] = b3[(w + 4 * i) * 16 + l15];

    int mbase = blockIdx.x * 64;
    for (int mi = 0; mi < 4; mi++) {
        int m0 = mbase + mi * 16;
        short8v ah[4];
        #pragma unroll
        for (int kc = 0; kc < 4; kc++) {
            int kof = kc * 32 + kofb;
            ah[kc] = *(const short8v*)(A + (size_t)(m0 + l15) * 128 + kof);
        }
        float4v acc1 = (float4v){0.f, 0.f, 0.f, 0.f};
        #pragma unroll
        for (int kc = 0; kc < 4; kc++) {
            acc1 = __builtin_amdgcn_mfma_f32_16x16x32_bf16(ah[kc], w2h[kc], acc1, 0, 0, 0);
            acc1 = __builtin_amdgcn_mfma_f32_16x16x32_bf16(ah[kc], w2l[kc], acc1, 0, 0, 0);
        }
        int buf = mi & 1;
        #pragma unroll
        for (int r = 0; r < 4; r++) {
            float v = fast_tanh(acc1[r] + b2v);
            ushort_t h = bf16rn(v);
            ushort_t lo2 = bf16rn(v - bf16tof(h));
            WF[buf][kg * 4 + r][w * 16 + l15] = (unsigned)h | ((unsigned)lo2 << 16);
        }
        __syncthreads();
        float4v acc2[2];
        acc2[0] = (float4v){0.f, 0.f, 0.f, 0.f};
        acc2[1] = (float4v){0.f, 0.f, 0.f, 0.f};
        #pragma unroll
        for (int kc = 0; kc < 2; kc++) {
            short8v a2h, a2l;
            #pragma unroll
            for (int j = 0; j < 8; j++) {
                unsigned u = WF[buf][l15][kc * 32 + kofb + j];
                a2h[j] = (short)(u & 0xFFFFu);
                a2l[j] = (short)(u >> 16);
            }
            #pragma unroll
            for (int i = 0; i < 2; i++) {
                acc2[i] = __builtin_amdgcn_mfma_f32_16x16x32_bf16(a2h, w3h[i][kc], acc2[i], 0, 0, 0);
                acc2[i] = __builtin_amdgcn_mfma_f32_16x16x32_bf16(a2h, w3l[i][kc], acc2[i], 0, 0, 0);
                acc2[i] = __builtin_amdgcn_mfma_f32_16x16x32_bf16(a2l, w3h[i][kc], acc2[i], 0, 0, 0);
            }
        }
        #pragma unroll
        for (int i = 0; i < 2; i++) {
            int n = (w + 4 * i) * 16 + l15;
            #pragma unroll
            for (int r = 0; r < 4; r++) {
                float v = fast_tanh(acc2[i][r] + b3v[i]);
                ushort_t h = bf16rn(v);
                OThi[buf][(kg * 4 + r) * 128 + n] = h;
                OTlo[buf][(kg * 4 + r) * 128 + n] = bf16rn(v - bf16tof(h));
            }
        }
        __syncthreads();
        *(uint4*)(OHi + (size_t)m0 * 128 + tid * 8) = *(const uint4*)(&OThi[buf][tid * 8]);
        *(uint4*)(OLo + (size_t)m0 * 128 + tid * 8) = *(const uint4*)(&OTlo[buf][tid * 8]);
    }
}

// ---------------- stage4: q1 -> LN -> psi packed u32, PT-staged stores ------
__global__ __launch_bounds__(256, 2) void gemm_s4(
    const ushort_t* __restrict__ Ahi, const ushort_t* __restrict__ Alo,
    const ushort_t* __restrict__ Whi, const ushort_t* __restrict__ Wlo,
    const float* __restrict__ bias,
    const float* __restrict__ lng, const float* __restrict__ lnb,
    unsigned* __restrict__ psiu)
{
    __shared__ float partS[2][4][16], partSS[2][4][16];
    __shared__ unsigned PT[256 * 65];
    int tid = threadIdx.x;
    int w = tid >> 6, l = tid & 63, l15 = l & 15, kg = l >> 4;
    int kofb = kg * 8;

    short8v bh[4][4], bl[4][4];
    #pragma unroll
    for (int i = 0; i < 4; i++) {
        int n = (w + 4 * i) * 16 + l15;
        #pragma unroll
        for (int kc = 0; kc < 4; kc++) {
            int kof = kc * 32 + kofb;
            bh[i][kc] = *(const short8v*)(Whi + (size_t)n * 128 + kof);
            bl[i][kc] = *(const short8v*)(Wlo + (size_t)n * 128 + kof);
        }
    }
    float bv[4], g4[4], be4[4];
    #pragma unroll
    for (int i = 0; i < 4; i++) {
        int n = (w + 4 * i) * 16 + l15;
        bv[i] = bias[n]; g4[i] = lng[n]; be4[i] = lnb[n];
    }

    int mbase = blockIdx.x * 64;
    int b = mbase >> 12, tbase = mbase & 4095;
    for (int mi = 0; mi < 4; mi++) {
        int m0 = mbase + mi * 16;
        short8v ah[4], al[4];
        #pragma unroll
        for (int kc = 0; kc < 4; kc++) {
            int kof = kc * 32 + kofb;
            ah[kc] = *(const short8v*)(Ahi + (size_t)(m0 + l15) * 128 + kof);
            al[kc] = *(const short8v*)(Alo + (size_t)(m0 + l15) * 128 + kof);
        }
        float4v acc[4];
        #pragma unroll
        for (int i = 0; i < 4; i++) acc[i] = (float4v){0.f, 0.f, 0.f, 0.f};
        #pragma unroll
        for (int kc = 0; kc < 4; kc++) {
            #pragma unroll
            for (int i = 0; i < 4; i++) {
                acc[i] = __builtin_amdgcn_mfma_f32_16x16x32_bf16(ah[kc], bh[i][kc], acc[i], 0, 0, 0);
                acc[i] = __builtin_amdgcn_mfma_f32_16x16x32_bf16(ah[kc], bl[i][kc], acc[i], 0, 0, 0);
                acc[i] = __builtin_amdgcn_mfma_f32_16x16x32_bf16(al[kc], bh[i][kc], acc[i], 0, 0, 0);
            }
        }
        float s[4] = {0, 0, 0, 0}, ss[4] = {0, 0, 0, 0};
        #pragma unroll
        for (int i = 0; i < 4; i++) {
            #pragma unroll
            for (int r = 0; r < 4; r++) {
                float v = acc[i][r] + bv[i];
                s[r] += v; ss[r] += v * v;
            }
        }
        #pragma unroll
        for (int r = 0; r < 4; r++) {
            #pragma unroll
            for (int off = 1; off < 16; off <<= 1) {
                s[r] += __shfl_xor(s[r], off);
                ss[r] += __shfl_xor(ss[r], off);
            }
        }
        int pb_ = mi & 1;
        if (l15 == 0) {
            #pragma unroll
            for (int r = 0; r < 4; r++) {
                partS[pb_][w][kg * 4 + r] = s[r];
                partSS[pb_][w][kg * 4 + r] = ss[r];
            }
        }
        __syncthreads();
        float mu[4], rstd[4];
        #pragma unroll
        for (int r = 0; r < 4; r++) {
            float ts = 0.f, tss = 0.f;
            #pragma unroll
            for (int wv = 0; wv < 4; wv++) {
                ts += partS[pb_][wv][kg * 4 + r];
                tss += partSS[pb_][wv][kg * 4 + r];
            }
            mu[r] = ts * (1.0f / 256.0f);
            float var = tss * (1.0f / 256.0f) - mu[r] * mu[r];
            rstd[r] = rsqrtf(var + 1e-5f);
        }
        #pragma unroll
        for (int i = 0; i < 4; i++) {
            int n = (w + 4 * i) * 16 + l15;
            #pragma unroll
            for (int r = 0; r < 4; r++) {
                float v = (acc[i][r] + bv[i] - mu[r]) * rstd[r] * g4[i] + be4[i];
                ushort_t h = bf16rn(v);
                ushort_t lo2 = bf16rn(v - bf16tof(h));
                PT[n * 65 + mi * 16 + kg * 4 + r] = (unsigned)h | ((unsigned)lo2 << 16);
            }
        }
    }
    __syncthreads();
    int n = tid;
    size_t gb = ((size_t)(b * 256 + n)) * 4096 + tbase;
    #pragma unroll
    for (int j = 0; j < 16; j++) {
        uint4 v;
        v.x = PT[n * 65 + j * 4 + 0];
        v.y = PT[n * 65 + j * 4 + 1];
        v.z = PT[n * 65 + j * 4 + 2];
        v.w = PT[n * 65 + j * 4 + 3];
        *(uint4*)(psiu + gb + j * 4) = v;
    }
}

// ---------------- K3a: evolve via MFMA; psi packed u32 in, f32 out ----------
__global__ __launch_bounds__(256) void k3a_mfma(float* __restrict__ psi,
                                                const float* __restrict__ U)
{
    __shared__ unsigned QP[64 * 261];
    int bid = blockIdx.x;
    int b = bid >> 6, c = (bid >> 4) & 3, tc = bid & 15;
    int t0 = tc * 256;
    int tid = threadIdx.x;
    int w = tid >> 6, l = tid & 63;
    int l15 = l & 15, kq = l >> 4;
    size_t gbase = ((size_t)(b * 256 + c * 64)) * TT + t0;
    const unsigned* psiu = (const unsigned*)psi;

    for (int i = 0; i < 16; i++) {
        int r_ = i * 4 + w;
        int t4 = l * 4;
        uint4 v = *(const uint4*)(psiu + gbase + (size_t)r_ * TT + t4);
        QP[r_ * 261 + t4 + 0] = v.x;
        QP[r_ * 261 + t4 + 1] = v.y;
        QP[r_ * 261 + t4 + 2] = v.z;
        QP[r_ * 261 + t4 + 3] = v.w;
    }
    __syncthreads();

    short8v ua_hi[2], ua_lo[2];
    #pragma unroll
    for (int kc = 0; kc < 2; kc++) {
        #pragma unroll
        for (int j = 0; j < 8; j++) {
            float v = U[c * 4096 + (w * 16 + l15) * 64 + kc * 32 + kq * 8 + j];
            ushort_t h = bf16rn(v);
            ua_hi[kc][j] = (short)h;
            ua_lo[kc][j] = (short)bf16rn(v - bf16tof(h));
        }
    }

    for (int nt = 0; nt < 16; nt++) {
        float4v acc = (float4v){0.f, 0.f, 0.f, 0.f};
        #pragma unroll
        for (int kc = 0; kc < 2; kc++) {
            short8v b_hi, b_lo;
            #pragma unroll
            for (int j = 0; j < 8; j++) {
                unsigned u = QP[(kc * 32 + kq * 8 + j) * 261 + nt * 16 + l15];
                b_hi[j] = (short)(u & 0xFFFFu);
                b_lo[j] = (short)(u >> 16);
            }
            acc = __builtin_amdgcn_mfma_f32_16x16x32_bf16(ua_hi[kc], b_hi, acc, 0, 0, 0);
            acc = __builtin_amdgcn_mfma_f32_16x16x32_bf16(ua_hi[kc], b_lo, acc, 0, 0, 0);
            acc = __builtin_amdgcn_mfma_f32_16x16x32_bf16(ua_lo[kc], b_hi, acc, 0, 0, 0);
        }
        #pragma unroll
        for (int r = 0; r < 4; r++) {
            int e = w * 16 + kq * 4 + r;
            psi[gbase + (size_t)e * TT + nt * 16 + l15] = acc[r];
        }
    }
}

// ---------------- K3b: 3-trip register FFT (16 pts/thread), sym unpack ------
__global__ __launch_bounds__(256, 2) void k3b_fft(const float* __restrict__ ev,
                                                  float* __restrict__ msum8)
{
    __shared__ float re[4224], im[4224];
    int b = blockIdx.x, c = blockIdx.y, g = blockIdx.z;
    int tid = threadIdx.x;

    float macc[8];
    #pragma unroll
    for (int r = 0; r < 8; r++) macc[r] = 0.f;
    float macc8 = 0.f;

    size_t base = (((size_t)b * 4 + c) * 64 + (size_t)g * 8) * TT;
    for (int p = 0; p < 4; p++) {
        __syncthreads();
        for (int r = 0; r < 4; r++) {
            int t0 = (r * 256 + tid) * 4;
            float4 va = *(const float4*)(ev + base + (size_t)(2 * p) * TT + t0);
            float4 vb = *(const float4*)(ev + base + (size_t)(2 * p + 1) * TT + t0);
            #pragma unroll
            for (int j = 0; j < 4; j++) {
                int rv = __brev((unsigned)(t0 + j)) >> 20;
                re[SW(rv)] = (&va.x)[j];
                im[SW(rv)] = (&vb.x)[j];
            }
        }
        __syncthreads();

        #pragma unroll
        for (int trip = 0; trip < 3; trip++) {
            const int sh = trip * 4;
            int pos = tid & ((1 << sh) - 1);
            int grp = tid >> sh;
            int i0 = (grp << (sh + 4)) + pos;

            float yr[16], yi[16];
            #pragma unroll
            for (int j = 0; j < 16; j++) {
                int a = SW(i0 + (j << sh));
                yr[j] = re[a]; yi[j] = im[a];
            }
            float ang = -(float)pos / (float)(16 << sh);
            float t1r = __builtin_amdgcn_cosf(ang);
            float t1i = __builtin_amdgcn_sinf(ang);
            float t2r = t1r * t1r - t1i * t1i, t2i = 2.f * t1r * t1i;
            float t4r = t2r * t2r - t2i * t2i, t4i = 2.f * t2r * t2i;
            float t8r = t4r * t4r - t4i * t4i, t8i = 2.f * t4r * t4i;

            #pragma unroll
            for (int m = 0; m < 8; m++) {
                int j0 = 2 * m, j1 = j0 + 1;
                float tr = t8r * yr[j1] - t8i * yi[j1];
                float ti = t8r * yi[j1] + t8i * yr[j1];
                yr[j1] = yr[j0] - tr; yi[j1] = yi[j0] - ti;
                yr[j0] += tr;         yi[j0] += ti;
            }
            #pragma unroll
            for (int bs = 0; bs < 16; bs += 4) {
                {
                    int j0 = bs, j1 = bs + 2;
                    float tr = t4r * yr[j1] - t4i * yi[j1];
                    float ti = t4r * yi[j1] + t4i * yr[j1];
                    yr[j1] = yr[j0] - tr; yi[j1] = yi[j0] - ti;
                    yr[j0] += tr;         yi[j0] += ti;
                }
                {
                    int j0 = bs + 1, j1 = bs + 3;
                    float tr = t4i * yr[j1] + t4r * yi[j1];
                    float ti = t4i * yi[j1] - t4r * yr[j1];
                    yr[j1] = yr[j0] - tr; yi[j1] = yi[j0] - ti;
                    yr[j0] += tr;         yi[j0] += ti;
                }
            }
            {
                float wr = t2r, wi = t2i;
                #pragma unroll
                for (int j = 0; j < 4; j++) {
                    #pragma unroll
                    for (int bs = 0; bs < 16; bs += 8) {
                        int j0 = bs + j, j1 = j0 + 4;
                        float tr = wr * yr[j1] - wi * yi[j1];
                        float ti = wr * yi[j1] + wi * yr[j1];
                        yr[j1] = yr[j0] - tr; yi[j1] = yi[j0] - ti;
                        yr[j0] += tr;         yi[j0] += ti;
                    }
                    float nwr = (wr + wi) * 0.70710678f;
                    float nwi = (wi - wr) * 0.70710678f;
                    wr = nwr; wi = nwi;
                }
            }
            {
                float wr = t1r, wi = t1i;
                #pragma unroll
                for (int j = 0; j < 8; j++) {
                    int j0 = j, j1 = j + 8;
                    float tr = wr * yr[j1] - wi * yi[j1];
                    float ti = wr * yi[j1] + wi * yr[j1];
                    yr[j1] = yr[j0] - tr; yi[j1] = yi[j0] - ti;
                    yr[j0] += tr;         yi[j0] += ti;
                    float nwr = wr * 0.92387953f + wi * 0.38268343f;
                    float nwi = wi * 0.92387953f - wr * 0.38268343f;
                    wr = nwr; wi = nwi;
                }
            }
            #pragma unroll
            for (int j = 0; j < 16; j++) {
                int a = SW(i0 + (j << sh));
                re[a] = yr[j]; im[a] = yi[j];
            }
            __syncthreads();
        }

        for (int r = 0; r < 8; r++) {
            int k = tid + r * 256;
            int mk = (4096 - k) & 4095;
            float rk = re[SW(k)], ik = im[SW(k)];
            float rm = re[SW(mk)], imm = im[SW(mk)];
            float dA1 = rk + rm, dA2 = ik - imm;
            float dB1 = ik + imm, dB2 = rk - rm;
            float magA = 0.5f * sqrtf(dA1 * dA1 + dA2 * dA2);
            float magB = 0.5f * sqrtf(dB1 * dB1 + dB2 * dB2);
            macc[r] += magA + magB;
        }
        if (tid == 0) {
            float rk = re[SW(2048)], ik = im[SW(2048)];
            macc8 += fabsf(rk) + fabsf(ik);
        }
    }
    float* ms = msum8 + (((size_t)b * 4 + c) * 8 + g) * 4096;
    for (int r = 0; r < 8; r++) {
        int k = tid + r * 256;
        ms[k] = macc[r];
        if (k > 0) ms[4096 - k] = macc[r];
    }
    if (tid == 0) ms[2048] = macc8;
}

// ---------------- K4: sum partials + softmax-weighted self-dot --------------
__global__ __launch_bounds__(256) void k4_softdot(const float* __restrict__ msum8,
                                                  float* __restrict__ sa)
{
    __shared__ float m[4096];
    __shared__ float red[256];
    int bc = blockIdx.x, tid = threadIdx.x;
    const float* ms = msum8 + (size_t)bc * 8 * 4096;
    float lmax = -1e30f;
    for (int k = tid; k < 4096; k += 256) {
        float v = 0.f;
        #pragma unroll
        for (int g = 0; g < 8; g++) v += ms[g * 4096 + k];
        v *= (1.0f / 64.0f);
        m[k] = v;
        lmax = fmaxf(lmax, v);
    }
    red[tid] = lmax; __syncthreads();
    for (int s2 = 128; s2 > 0; s2 >>= 1) {
        if (tid < s2) red[tid] = fmaxf(red[tid], red[tid + s2]);
        __syncthreads();
    }
    float mx = red[0]; __syncthreads();
    float lsum = 0.f, ldot = 0.f;
    for (int k = tid; k < 4096; k += 256) {
        float e = expf(m[k] - mx);
        lsum += e; ldot += e * m[k];
    }
    red[tid] = lsum; __syncthreads();
    for (int s2 = 128; s2 > 0; s2 >>= 1) {
        if (tid < s2) red[tid] += red[tid + s2];
        __syncthreads();
    }
    float tsum = red[0]; __syncthreads();
    red[tid] = ldot; __syncthreads();
    for (int s2 = 128; s2 > 0; s2 >>= 1) {
        if (tid < s2) red[tid] += red[tid + s2];
        __syncthreads();
    }
    if (tid == 0) sa[bc] = red[0] / tsum;
}

// ---------------- K5: final tiny MLP per batch ------------------------------
__global__ void k5_head(const float* __restrict__ sa,
                        const float* __restrict__ w1, const float* __restrict__ b1,
                        const float* __restrict__ w2, const float* __restrict__ b2,
                        const float* __restrict__ strength,
                        float* __restrict__ out)
{
    int b = threadIdx.x;
    if (b >= 32) return;
    float s0 = sa[b * 4 + 0], s1 = sa[b * 4 + 1];
    float s2 = sa[b * 4 + 2], s3 = sa[b * 4 + 3];
    float h[32];
    #pragma unroll
    for (int j = 0; j < 32; j++)
        h[j] = tanhf(b1[j] + w1[j * 4 + 0] * s0 + w1[j * 4 + 1] * s1 +
                     w1[j * 4 + 2] * s2 + w1[j * 4 + 3] * s3);
    float st = strength[0];
    #pragma unroll
    for (int o = 0; o < 2; o++) {
        float a = b2[o];
        #pragma unroll
        for (int j = 0; j < 32; j++) a = fmaf(w2[o * 32 + j], h[j], a);
        out[b * 2 + o] = a * st;
    }
}

extern "C" void kernel_launch(void* const* d_in, const int* in_sizes, int n_in,
                              void* d_out, int out_size, void* d_ws, size_t ws_size,
                              hipStream_t stream)
{
    const float* x    = (const float*)d_in[0];
    const float* freq = (const float*)d_in[1];
    const float* pw1  = (const float*)d_in[2];
    const float* pb1  = (const float*)d_in[3];
    const float* pw2  = (const float*)d_in[4];
    const float* pb2  = (const float*)d_in[5];
    const float* wcw  = (const float*)d_in[6];
    const float* wcb  = (const float*)d_in[7];
    const float* ampc = (const float*)d_in[8];
    const float* qw1  = (const float*)d_in[9];
    const float* qb1  = (const float*)d_in[10];
    const float* qw2  = (const float*)d_in[11];
    const float* qb2  = (const float*)d_in[12];
    const float* lng  = (const float*)d_in[13];
    const float* lnb  = (const float*)d_in[14];
    const float* hams = (const float*)d_in[15];
    const float* iw1  = (const float*)d_in[16];
    const float* ib1  = (const float*)d_in[17];
    const float* iw2  = (const float*)d_in[18];
    const float* ib2  = (const float*)d_in[19];
    const float* istr = (const float*)d_in[20];

    char* wsb = (char*)d_ws;
    ushort_t* AHi = (ushort_t*)(wsb + 0);           // q1 hi (dead after stage4)
    ushort_t* ALo = (ushort_t*)(wsb + 33554432);    // q1 lo
    ushort_t* Bwcf = (ushort_t*)(wsb + 67108864);   // wcf single plane (67MB)
    float*    psi = (float*)(wsb + 67108864);       // overlays wcf (dead by stage4)
    float*    msum8 = (float*)(wsb + 0);            // overlays q1 (dead after stage4)
    float*    U    = (float*)(wsb + 201326592);
    float*    sa   = (float*)(wsb + 201392128);
    ushort_t* wb   = (ushort_t*)(wsb + 203489792);
    ushort_t *pw2hi = wb,          *pw2lo = wb + 32768;
    ushort_t *wcwhi = wb + 65536,  *wcwlo = wb + 73728;
    ushort_t *qw1hi = wb + 81920,  *qw1lo = wb + 90112;
    ushort_t *qw2hi = wb + 98304,  *qw2lo = wb + 131072;
    float* out = (float*)d_out;

    k1_expm<<<4, 256, 0, stream>>>(hams, U);
    split_all<<<320, 256, 0, stream>>>(pw2, wcw, qw1, qw2, wb);

    // stage1 (fused h1): x -> wcf (single bf16 plane)
    gemm_s1<<<2048, 256, 0, stream>>>(pw2hi, pw2lo, pb2, x, pw1, pb1,
                                      freq, ampc, Bwcf);
    // stage2+3 fused: wcf -> wf -> q1 (hi/lo)
    s23_v2<<<2048, 256, 0, stream>>>(Bwcf, wcwhi, wcwlo, wcb,
        qw1hi, qw1lo, qb1, AHi, ALo);
    // stage4: q1 -> LN -> psi transposed (packed bf16 hi|lo u32)
    gemm_s4<<<2048, 256, 0, stream>>>(AHi, ALo, qw2hi, qw2lo, qb2,
        lng, lnb, (unsigned*)psi);

    k3a_mfma<<<2048, 256, 0, stream>>>(psi, U);
    k3b_fft<<<dim3(32, 4, 8), 256, 0, stream>>>(psi, msum8);
    k4_softdot<<<128, 256, 0, stream>>>(msum8, sa);
    k5_head<<<1, 64, 0, stream>>>(sa, iw1, ib1, iw2, ib2, istr, out);
}

// Round 12
// 352.078 us; speedup vs baseline: 1.0383x; 1.0383x over previous
//
#include <hip/hip_runtime.h>
#include <hip/hip_bf16.h>

#define TT 4096
#define BB 32

typedef unsigned short ushort_t;
typedef __attribute__((ext_vector_type(8))) short short8v;
typedef __attribute__((ext_vector_type(4))) float float4v;

__device__ inline ushort_t bf16rn(float v) {
    unsigned u = __float_as_uint(v);
    unsigned r = (u + 0x7FFFu + ((u >> 16) & 1u)) >> 16;
    return (ushort_t)r;
}
__device__ inline float bf16tof(ushort_t h) {
    return __uint_as_float(((unsigned)h) << 16);
}
__device__ inline int SW(int i) { return i + (i >> 5); }

__device__ inline float fast_tanh(float x) {
    float e = __builtin_amdgcn_exp2f(x * 2.8853900817779268f);
    return 1.0f - 2.0f * __builtin_amdgcn_rcpf(e + 1.0f);
}
__device__ inline float fast_sin(float x) {
    return __builtin_amdgcn_sinf(x * 0.15915494309189535f);
}

// ---------------- K1: expm(hams*DT) via Taylor ------------------------------
__global__ __launch_bounds__(256) void k1_expm(const float* __restrict__ hams,
                                               float* __restrict__ U)
{
    int c = blockIdx.x, tid = threadIdx.x;
    __shared__ float M[4096], P[4096], Acc[4096];
    const float* H = hams + c * 4096;
    for (int k = tid; k < 4096; k += 256) {
        float m = H[k] * 0.1f;
        M[k] = m; P[k] = m;
        Acc[k] = m + (((k >> 6) == (k & 63)) ? 1.0f : 0.0f);
    }
    __syncthreads();
    int j = tid & 63;
    float mcol[64];
    #pragma unroll
    for (int k = 0; k < 64; k++) mcol[k] = M[k * 64 + j];
    for (int term = 2; term <= 8; term++) {
        float inv = 1.0f / (float)term;
        float np_[16];
        #pragma unroll
        for (int r = 0; r < 16; r++) {
            int i = (tid >> 6) + 4 * r;
            float a = 0.f;
            #pragma unroll
            for (int k = 0; k < 64; k++) a = fmaf(P[i * 64 + k], mcol[k], a);
            np_[r] = a * inv;
        }
        __syncthreads();
        #pragma unroll
        for (int r = 0; r < 16; r++) {
            int i = (tid >> 6) + 4 * r;
            P[i * 64 + j] = np_[r];
            Acc[i * 64 + j] += np_[r];
        }
        __syncthreads();
    }
    for (int k = tid; k < 4096; k += 256) U[c * 4096 + k] = Acc[k];
}

// ---------------- all weight f32 -> bf16 hi/lo planes -----------------------
__global__ void split_all(const float* __restrict__ pw2, const float* __restrict__ wcw,
                          const float* __restrict__ qw1, const float* __restrict__ qw2,
                          ushort_t* __restrict__ wb)
{
    int i = blockIdx.x * 256 + threadIdx.x;
    const float* src; ushort_t *hi, *lo; int off;
    if (i < 32768)      { src = pw2; hi = wb;          lo = wb + 32768;  off = i; }
    else if (i < 40960) { src = wcw; hi = wb + 65536;  lo = wb + 73728;  off = i - 32768; }
    else if (i < 49152) { src = qw1; hi = wb + 81920;  lo = wb + 90112;  off = i - 40960; }
    else                { src = qw2; hi = wb + 98304;  lo = wb + 131072; off = i - 49152; }
    float v = src[off];
    ushort_t h = bf16rn(v);
    hi[off] = h;
    lo[off] = bf16rn(v - bf16tof(h));
}

// ---------------- stage1: x -> wcf (single bf16 plane, coalesced store) -----
__global__ __launch_bounds__(256, 2) void gemm_s1(
    const ushort_t* __restrict__ Whi, const ushort_t* __restrict__ Wlo,
    const float* __restrict__ bias,
    const float* __restrict__ x, const float* __restrict__ pw1,
    const float* __restrict__ pb1,
    const float* __restrict__ freq, const float* __restrict__ ampc,
    ushort_t* __restrict__ O)
{
    __shared__ ushort_t OT[2][2048];
    int tid = threadIdx.x;
    int w = tid >> 6, l = tid & 63, l15 = l & 15, kg = l >> 4;
    int kofb = kg * 8;

    short8v bh[4][4], bl[4][4];
    #pragma unroll
    for (int i = 0; i < 4; i++) {
        int n = (w + 4 * i) * 16 + l15;
        #pragma unroll
        for (int kc = 0; kc < 4; kc++) {
            int kof = kc * 32 + kofb;
            bh[i][kc] = *(const short8v*)(Whi + (size_t)n * 128 + kof);
            bl[i][kc] = *(const short8v*)(Wlo + (size_t)n * 128 + kof);
        }
    }
    float am = ampc[0];
    float fr[2], ba[2], bp[2];
    #pragma unroll
    for (int i = 0; i < 2; i++) {
        int f = (w + 4 * i) * 16 + l15;
        fr[i] = freq[f]; ba[i] = bias[f]; bp[i] = bias[128 + f];
    }

    int mbase = blockIdx.x * 64;
    for (int mi = 0; mi < 4; mi++) {
        int m0 = mbase + mi * 16;
        float xv = x[m0 + l15];
        short8v ah[4], al[4];
        #pragma unroll
        for (int kc = 0; kc < 4; kc++) {
            int k0 = kc * 32 + kofb;
            float4 w0 = *(const float4*)(pw1 + k0);
            float4 w1v = *(const float4*)(pw1 + k0 + 4);
            float4 b0 = *(const float4*)(pb1 + k0);
            float4 b1v = *(const float4*)(pb1 + k0 + 4);
            #pragma unroll
            for (int j = 0; j < 8; j++) {
                float wj = (j < 4) ? (&w0.x)[j] : (&w1v.x)[j - 4];
                float bj = (j < 4) ? (&b0.x)[j] : (&b1v.x)[j - 4];
                float v = fast_tanh(fmaf(xv, wj, bj));
                ushort_t h = bf16rn(v);
                ah[kc][j] = (short)h;
                al[kc][j] = (short)bf16rn(v - bf16tof(h));
            }
        }
        float4v acc[4];
        #pragma unroll
        for (int i = 0; i < 4; i++) acc[i] = (float4v){0.f, 0.f, 0.f, 0.f};
        #pragma unroll
        for (int kc = 0; kc < 4; kc++) {
            #pragma unroll
            for (int i = 0; i < 4; i++) {
                acc[i] = __builtin_amdgcn_mfma_f32_16x16x32_bf16(ah[kc], bh[i][kc], acc[i], 0, 0, 0);
                acc[i] = __builtin_amdgcn_mfma_f32_16x16x32_bf16(ah[kc], bl[i][kc], acc[i], 0, 0, 0);
                acc[i] = __builtin_amdgcn_mfma_f32_16x16x32_bf16(al[kc], bh[i][kc], acc[i], 0, 0, 0);
            }
        }
        int buf = mi & 1;
        #pragma unroll
        for (int i = 0; i < 2; i++) {
            int f = (w + 4 * i) * 16 + l15;
            #pragma unroll
            for (int r = 0; r < 4; r++) {
                int m = m0 + kg * 4 + r;
                float timev = 6.283185307179586f * (float)(m & 4095) / 4095.0f;
                float a = fast_tanh(acc[i][r] + ba[i]) * am;
                float ph = acc[i + 2][r] + bp[i];
                float v = a * fast_sin(fmaf(fr[i], timev, ph));
                OT[buf][(kg * 4 + r) * 128 + f] = bf16rn(v);
            }
        }
        __syncthreads();
        *(uint4*)(O + (size_t)m0 * 128 + tid * 8) = *(const uint4*)(&OT[buf][tid * 8]);
    }
}

// ---------------- s23: wcf(bf16) -> wf -> q1 (hi/lo, coalesced stores) ------
__global__ __launch_bounds__(256, 2) void s23_v2(
    const ushort_t* __restrict__ A,
    const ushort_t* __restrict__ W2hi, const ushort_t* __restrict__ W2lo,
    const float* __restrict__ b2,
    const ushort_t* __restrict__ W3hi, const ushort_t* __restrict__ W3lo,
    const float* __restrict__ b3,
    ushort_t* __restrict__ OHi, ushort_t* __restrict__ OLo)
{
    __shared__ unsigned WF[2][16][65];
    __shared__ ushort_t OThi[2][2048], OTlo[2][2048];
    int tid = threadIdx.x;
    int w = tid >> 6, l = tid & 63, l15 = l & 15, kg = l >> 4;
    int kofb = kg * 8;

    short8v w2h[4], w2l[4];
    #pragma unroll
    for (int kc = 0; kc < 4; kc++) {
        int n = w * 16 + l15;
        int kof = kc * 32 + kofb;
        w2h[kc] = *(const short8v*)(W2hi + (size_t)n * 128 + kof);
        w2l[kc] = *(const short8v*)(W2lo + (size_t)n * 128 + kof);
    }
    short8v w3h[2][2], w3l[2][2];
    #pragma unroll
    for (int i = 0; i < 2; i++) {
        int n = (w + 4 * i) * 16 + l15;
        #pragma unroll
        for (int kc = 0; kc < 2; kc++) {
            int kof = kc * 32 + kofb;
            w3h[i][kc] = *(const short8v*)(W3hi + (size_t)n * 64 + kof);
            w3l[i][kc] = *(const short8v*)(W3lo + (size_t)n * 64 + kof);
        }
    }
    float b2v = b2[w * 16 + l15];
    float b3v[2];
    #pragma unroll
    for (int i = 0; i < 2; i++) b3v[i] = b3[(w + 4 * i) * 16 + l15];

    int mbase = blockIdx.x * 64;
    for (int mi = 0; mi < 4; mi++) {
        int m0 = mbase + mi * 16;
        short8v ah[4];
        #pragma unroll
        for (int kc = 0; kc < 4; kc++) {
            int kof = kc * 32 + kofb;
            ah[kc] = *(const short8v*)(A + (size_t)(m0 + l15) * 128 + kof);
        }
        float4v acc1 = (float4v){0.f, 0.f, 0.f, 0.f};
        #pragma unroll
        for (int kc = 0; kc < 4; kc++) {
            acc1 = __builtin_amdgcn_mfma_f32_16x16x32_bf16(ah[kc], w2h[kc], acc1, 0, 0, 0);
            acc1 = __builtin_amdgcn_mfma_f32_16x16x32_bf16(ah[kc], w2l[kc], acc1, 0, 0, 0);
        }
        int buf = mi & 1;
        #pragma unroll
        for (int r = 0; r < 4; r++) {
            float v = fast_tanh(acc1[r] + b2v);
            ushort_t h = bf16rn(v);
            ushort_t lo2 = bf16rn(v - bf16tof(h));
            WF[buf][kg * 4 + r][w * 16 + l15] = (unsigned)h | ((unsigned)lo2 << 16);
        }
        __syncthreads();
        float4v acc2[2];
        acc2[0] = (float4v){0.f, 0.f, 0.f, 0.f};
        acc2[1] = (float4v){0.f, 0.f, 0.f, 0.f};
        #pragma unroll
        for (int kc = 0; kc < 2; kc++) {
            short8v a2h, a2l;
            #pragma unroll
            for (int j = 0; j < 8; j++) {
                unsigned u = WF[buf][l15][kc * 32 + kofb + j];
                a2h[j] = (short)(u & 0xFFFFu);
                a2l[j] = (short)(u >> 16);
            }
            #pragma unroll
            for (int i = 0; i < 2; i++) {
                acc2[i] = __builtin_amdgcn_mfma_f32_16x16x32_bf16(a2h, w3h[i][kc], acc2[i], 0, 0, 0);
                acc2[i] = __builtin_amdgcn_mfma_f32_16x16x32_bf16(a2h, w3l[i][kc], acc2[i], 0, 0, 0);
                acc2[i] = __builtin_amdgcn_mfma_f32_16x16x32_bf16(a2l, w3h[i][kc], acc2[i], 0, 0, 0);
            }
        }
        #pragma unroll
        for (int i = 0; i < 2; i++) {
            int n = (w + 4 * i) * 16 + l15;
            #pragma unroll
            for (int r = 0; r < 4; r++) {
                float v = fast_tanh(acc2[i][r] + b3v[i]);
                ushort_t h = bf16rn(v);
                OThi[buf][(kg * 4 + r) * 128 + n] = h;
                OTlo[buf][(kg * 4 + r) * 128 + n] = bf16rn(v - bf16tof(h));
            }
        }
        __syncthreads();
        *(uint4*)(OHi + (size_t)m0 * 128 + tid * 8) = *(const uint4*)(&OThi[buf][tid * 8]);
        *(uint4*)(OLo + (size_t)m0 * 128 + tid * 8) = *(const uint4*)(&OTlo[buf][tid * 8]);
    }
}

// ---------------- stage4+evolve fused: q1 -> LN -> U@psi -> psi packed u32 --
__global__ __launch_bounds__(256, 2) void gemm_s4e(
    const ushort_t* __restrict__ Ahi, const ushort_t* __restrict__ Alo,
    const ushort_t* __restrict__ Whi, const ushort_t* __restrict__ Wlo,
    const float* __restrict__ bias,
    const float* __restrict__ lng, const float* __restrict__ lnb,
    const float* __restrict__ U,
    unsigned* __restrict__ psiu)
{
    __shared__ float partS[2][4][16], partSS[2][4][16];
    __shared__ unsigned PT[256 * 33];    // [n][t_local], stride 33
    int tid = threadIdx.x;
    int w = tid >> 6, l = tid & 63, l15 = l & 15, kg = l >> 4;
    int kofb = kg * 8;

    short8v bh[4][4], bl[4][4];
    #pragma unroll
    for (int i = 0; i < 4; i++) {
        int n = (w + 4 * i) * 16 + l15;
        #pragma unroll
        for (int kc = 0; kc < 4; kc++) {
            int kof = kc * 32 + kofb;
            bh[i][kc] = *(const short8v*)(Whi + (size_t)n * 128 + kof);
            bl[i][kc] = *(const short8v*)(Wlo + (size_t)n * 128 + kof);
        }
    }
    float bv[4], g4[4], be4[4];
    #pragma unroll
    for (int i = 0; i < 4; i++) {
        int n = (w + 4 * i) * 16 + l15;
        bv[i] = bias[n]; g4[i] = lng[n]; be4[i] = lnb[n];
    }

    int mbase = blockIdx.x * 32;
    int b = mbase >> 12, tbase = mbase & 4095;
    for (int mi = 0; mi < 2; mi++) {
        int m0 = mbase + mi * 16;
        short8v ah[4], al[4];
        #pragma unroll
        for (int kc = 0; kc < 4; kc++) {
            int kof = kc * 32 + kofb;
            ah[kc] = *(const short8v*)(Ahi + (size_t)(m0 + l15) * 128 + kof);
            al[kc] = *(const short8v*)(Alo + (size_t)(m0 + l15) * 128 + kof);
        }
        float4v acc[4];
        #pragma unroll
        for (int i = 0; i < 4; i++) acc[i] = (float4v){0.f, 0.f, 0.f, 0.f};
        #pragma unroll
        for (int kc = 0; kc < 4; kc++) {
            #pragma unroll
            for (int i = 0; i < 4; i++) {
                acc[i] = __builtin_amdgcn_mfma_f32_16x16x32_bf16(ah[kc], bh[i][kc], acc[i], 0, 0, 0);
                acc[i] = __builtin_amdgcn_mfma_f32_16x16x32_bf16(ah[kc], bl[i][kc], acc[i], 0, 0, 0);
                acc[i] = __builtin_amdgcn_mfma_f32_16x16x32_bf16(al[kc], bh[i][kc], acc[i], 0, 0, 0);
            }
        }
        float s[4] = {0, 0, 0, 0}, ss[4] = {0, 0, 0, 0};
        #pragma unroll
        for (int i = 0; i < 4; i++) {
            #pragma unroll
            for (int r = 0; r < 4; r++) {
                float v = acc[i][r] + bv[i];
                s[r] += v; ss[r] += v * v;
            }
        }
        #pragma unroll
        for (int r = 0; r < 4; r++) {
            #pragma unroll
            for (int off = 1; off < 16; off <<= 1) {
                s[r] += __shfl_xor(s[r], off);
                ss[r] += __shfl_xor(ss[r], off);
            }
        }
        int pb_ = mi & 1;
        if (l15 == 0) {
            #pragma unroll
            for (int r = 0; r < 4; r++) {
                partS[pb_][w][kg * 4 + r] = s[r];
                partSS[pb_][w][kg * 4 + r] = ss[r];
            }
        }
        __syncthreads();
        float mu[4], rstd[4];
        #pragma unroll
        for (int r = 0; r < 4; r++) {
            float ts = 0.f, tss = 0.f;
            #pragma unroll
            for (int wv = 0; wv < 4; wv++) {
                ts += partS[pb_][wv][kg * 4 + r];
                tss += partSS[pb_][wv][kg * 4 + r];
            }
            mu[r] = ts * (1.0f / 256.0f);
            float var = tss * (1.0f / 256.0f) - mu[r] * mu[r];
            rstd[r] = rsqrtf(var + 1e-5f);
        }
        #pragma unroll
        for (int i = 0; i < 4; i++) {
            int n = (w + 4 * i) * 16 + l15;
            #pragma unroll
            for (int r = 0; r < 4; r++) {
                float v = (acc[i][r] + bv[i] - mu[r]) * rstd[r] * g4[i] + be4[i];
                ushort_t h = bf16rn(v);
                ushort_t lo2 = bf16rn(v - bf16tof(h));
                PT[n * 33 + mi * 16 + kg * 4 + r] = (unsigned)h | ((unsigned)lo2 << 16);
            }
        }
    }
    __syncthreads();

    // phase 2: evolve, wave w owns component c = w
    int c = w;
    size_t gb = ((size_t)(b * 256 + c * 64)) * 4096 + tbase;
    for (int et = 0; et < 4; et++) {
        short8v ua_h[2], ua_l[2];
        #pragma unroll
        for (int kc = 0; kc < 2; kc++) {
            #pragma unroll
            for (int j = 0; j < 8; j++) {
                float v = U[c * 4096 + (et * 16 + l15) * 64 + kc * 32 + kofb + j];
                ushort_t h = bf16rn(v);
                ua_h[kc][j] = (short)h;
                ua_l[kc][j] = (short)bf16rn(v - bf16tof(h));
            }
        }
        #pragma unroll
        for (int tt = 0; tt < 2; tt++) {
            float4v acc = (float4v){0.f, 0.f, 0.f, 0.f};
            #pragma unroll
            for (int kc = 0; kc < 2; kc++) {
                short8v b_h, b_l;
                #pragma unroll
                for (int j = 0; j < 8; j++) {
                    unsigned u = PT[(c * 64 + kc * 32 + kofb + j) * 33 + tt * 16 + l15];
                    b_h[j] = (short)(u & 0xFFFFu);
                    b_l[j] = (short)(u >> 16);
                }
                acc = __builtin_amdgcn_mfma_f32_16x16x32_bf16(ua_h[kc], b_h, acc, 0, 0, 0);
                acc = __builtin_amdgcn_mfma_f32_16x16x32_bf16(ua_h[kc], b_l, acc, 0, 0, 0);
                acc = __builtin_amdgcn_mfma_f32_16x16x32_bf16(ua_l[kc], b_h, acc, 0, 0, 0);
            }
            #pragma unroll
            for (int r = 0; r < 4; r++) {
                int e = et * 16 + kg * 4 + r;
                float v = acc[r];
                ushort_t h = bf16rn(v);
                ushort_t lo2 = bf16rn(v - bf16tof(h));
                psiu[gb + (size_t)e * 4096 + tt * 16 + l15] =
                    (unsigned)h | ((unsigned)lo2 << 16);
            }
        }
    }
}

// ---------------- K3b: 3-trip register FFT, packed-u32 input ----------------
__global__ __launch_bounds__(256, 2) void k3b_fft(const unsigned* __restrict__ ev,
                                                  float* __restrict__ msum8)
{
    __shared__ float re[4224], im[4224];
    int b = blockIdx.x, c = blockIdx.y, g = blockIdx.z;
    int tid = threadIdx.x;

    float macc[8];
    #pragma unroll
    for (int r = 0; r < 8; r++) macc[r] = 0.f;
    float macc8 = 0.f;

    size_t base = (((size_t)b * 4 + c) * 64 + (size_t)g * 8) * TT;
    for (int p = 0; p < 4; p++) {
        __syncthreads();
        for (int r = 0; r < 4; r++) {
            int t0 = (r * 256 + tid) * 4;
            uint4 va = *(const uint4*)(ev + base + (size_t)(2 * p) * TT + t0);
            uint4 vb = *(const uint4*)(ev + base + (size_t)(2 * p + 1) * TT + t0);
            #pragma unroll
            for (int j = 0; j < 4; j++) {
                int rv = __brev((unsigned)(t0 + j)) >> 20;
                unsigned ua = (&va.x)[j], ub = (&vb.x)[j];
                re[SW(rv)] = bf16tof((ushort_t)(ua & 0xFFFFu)) + bf16tof((ushort_t)(ua >> 16));
                im[SW(rv)] = bf16tof((ushort_t)(ub & 0xFFFFu)) + bf16tof((ushort_t)(ub >> 16));
            }
        }
        __syncthreads();

        #pragma unroll
        for (int trip = 0; trip < 3; trip++) {
            const int sh = trip * 4;
            int pos = tid & ((1 << sh) - 1);
            int grp = tid >> sh;
            int i0 = (grp << (sh + 4)) + pos;

            float yr[16], yi[16];
            #pragma unroll
            for (int j = 0; j < 16; j++) {
                int a = SW(i0 + (j << sh));
                yr[j] = re[a]; yi[j] = im[a];
            }
            float ang = -(float)pos / (float)(16 << sh);
            float t1r = __builtin_amdgcn_cosf(ang);
            float t1i = __builtin_amdgcn_sinf(ang);
            float t2r = t1r * t1r - t1i * t1i, t2i = 2.f * t1r * t1i;
            float t4r = t2r * t2r - t2i * t2i, t4i = 2.f * t2r * t2i;
            float t8r = t4r * t4r - t4i * t4i, t8i = 2.f * t4r * t4i;

            #pragma unroll
            for (int m = 0; m < 8; m++) {
                int j0 = 2 * m, j1 = j0 + 1;
                float tr = t8r * yr[j1] - t8i * yi[j1];
                float ti = t8r * yi[j1] + t8i * yr[j1];
                yr[j1] = yr[j0] - tr; yi[j1] = yi[j0] - ti;
                yr[j0] += tr;         yi[j0] += ti;
            }
            #pragma unroll
            for (int bs = 0; bs < 16; bs += 4) {
                {
                    int j0 = bs, j1 = bs + 2;
                    float tr = t4r * yr[j1] - t4i * yi[j1];
                    float ti = t4r * yi[j1] + t4i * yr[j1];
                    yr[j1] = yr[j0] - tr; yi[j1] = yi[j0] - ti;
                    yr[j0] += tr;         yi[j0] += ti;
                }
                {
                    int j0 = bs + 1, j1 = bs + 3;
                    float tr = t4i * yr[j1] + t4r * yi[j1];
                    float ti = t4i * yi[j1] - t4r * yr[j1];
                    yr[j1] = yr[j0] - tr; yi[j1] = yi[j0] - ti;
                    yr[j0] += tr;         yi[j0] += ti;
                }
            }
            {
                float wr = t2r, wi = t2i;
                #pragma unroll
                for (int j = 0; j < 4; j++) {
                    #pragma unroll
                    for (int bs = 0; bs < 16; bs += 8) {
                        int j0 = bs + j, j1 = j0 + 4;
                        float tr = wr * yr[j1] - wi * yi[j1];
                        float ti = wr * yi[j1] + wi * yr[j1];
                        yr[j1] = yr[j0] - tr; yi[j1] = yi[j0] - ti;
                        yr[j0] += tr;         yi[j0] += ti;
                    }
                    float nwr = (wr + wi) * 0.70710678f;
                    float nwi = (wi - wr) * 0.70710678f;
                    wr = nwr; wi = nwi;
                }
            }
            {
                float wr = t1r, wi = t1i;
                #pragma unroll
                for (int j = 0; j < 8; j++) {
                    int j0 = j, j1 = j + 8;
                    float tr = wr * yr[j1] - wi * yi[j1];
                    float ti = wr * yi[j1] + wi * yr[j1];
                    yr[j1] = yr[j0] - tr; yi[j1] = yi[j0] - ti;
                    yr[j0] += tr;         yi[j0] += ti;
                    float nwr = wr * 0.92387953f + wi * 0.38268343f;
                    float nwi = wi * 0.92387953f - wr * 0.38268343f;
                    wr = nwr; wi = nwi;
                }
            }
            #pragma unroll
            for (int j = 0; j < 16; j++) {
                int a = SW(i0 + (j << sh));
                re[a] = yr[j]; im[a] = yi[j];
            }
            __syncthreads();
        }

        for (int r = 0; r < 8; r++) {
            int k = tid + r * 256;
            int mk = (4096 - k) & 4095;
            float rk = re[SW(k)], ik = im[SW(k)];
            float rm = re[SW(mk)], imm = im[SW(mk)];
            float dA1 = rk + rm, dA2 = ik - imm;
            float dB1 = ik + imm, dB2 = rk - rm;
            float magA = 0.5f * sqrtf(dA1 * dA1 + dA2 * dA2);
            float magB = 0.5f * sqrtf(dB1 * dB1 + dB2 * dB2);
            macc[r] += magA + magB;
        }
        if (tid == 0) {
            float rk = re[SW(2048)], ik = im[SW(2048)];
            macc8 += fabsf(rk) + fabsf(ik);
        }
    }
    float* ms = msum8 + (((size_t)b * 4 + c) * 8 + g) * 4096;
    for (int r = 0; r < 8; r++) {
        int k = tid + r * 256;
        ms[k] = macc[r];
        if (k > 0) ms[4096 - k] = macc[r];
    }
    if (tid == 0) ms[2048] = macc8;
}

// ---------------- K4: sum partials + softmax-weighted self-dot --------------
__global__ __launch_bounds__(256) void k4_softdot(const float* __restrict__ msum8,
                                                  float* __restrict__ sa)
{
    __shared__ float m[4096];
    __shared__ float red[256];
    int bc = blockIdx.x, tid = threadIdx.x;
    const float* ms = msum8 + (size_t)bc * 8 * 4096;
    float lmax = -1e30f;
    for (int k = tid; k < 4096; k += 256) {
        float v = 0.f;
        #pragma unroll
        for (int g = 0; g < 8; g++) v += ms[g * 4096 + k];
        v *= (1.0f / 64.0f);
        m[k] = v;
        lmax = fmaxf(lmax, v);
    }
    red[tid] = lmax; __syncthreads();
    for (int s2 = 128; s2 > 0; s2 >>= 1) {
        if (tid < s2) red[tid] = fmaxf(red[tid], red[tid + s2]);
        __syncthreads();
    }
    float mx = red[0]; __syncthreads();
    float lsum = 0.f, ldot = 0.f;
    for (int k = tid; k < 4096; k += 256) {
        float e = expf(m[k] - mx);
        lsum += e; ldot += e * m[k];
    }
    red[tid] = lsum; __syncthreads();
    for (int s2 = 128; s2 > 0; s2 >>= 1) {
        if (tid < s2) red[tid] += red[tid + s2];
        __syncthreads();
    }
    float tsum = red[0]; __syncthreads();
    red[tid] = ldot; __syncthreads();
    for (int s2 = 128; s2 > 0; s2 >>= 1) {
        if (tid < s2) red[tid] += red[tid + s2];
        __syncthreads();
    }
    if (tid == 0) sa[bc] = red[0] / tsum;
}

// ---------------- K5: final tiny MLP per batch ------------------------------
__global__ void k5_head(const float* __restrict__ sa,
                        const float* __restrict__ w1, const float* __restrict__ b1,
                        const float* __restrict__ w2, const float* __restrict__ b2,
                        const float* __restrict__ strength,
                        float* __restrict__ out)
{
    int b = threadIdx.x;
    if (b >= 32) return;
    float s0 = sa[b * 4 + 0], s1 = sa[b * 4 + 1];
    float s2 = sa[b * 4 + 2], s3 = sa[b * 4 + 3];
    float h[32];
    #pragma unroll
    for (int j = 0; j < 32; j++)
        h[j] = tanhf(b1[j] + w1[j * 4 + 0] * s0 + w1[j * 4 + 1] * s1 +
                     w1[j * 4 + 2] * s2 + w1[j * 4 + 3] * s3);
    float st = strength[0];
    #pragma unroll
    for (int o = 0; o < 2; o++) {
        float a = b2[o];
        #pragma unroll
        for (int j = 0; j < 32; j++) a = fmaf(w2[o * 32 + j], h[j], a);
        out[b * 2 + o] = a * st;
    }
}

extern "C" void kernel_launch(void* const* d_in, const int* in_sizes, int n_in,
                              void* d_out, int out_size, void* d_ws, size_t ws_size,
                              hipStream_t stream)
{
    const float* x    = (const float*)d_in[0];
    const float* freq = (const float*)d_in[1];
    const float* pw1  = (const float*)d_in[2];
    const float* pb1  = (const float*)d_in[3];
    const float* pw2  = (const float*)d_in[4];
    const float* pb2  = (const float*)d_in[5];
    const float* wcw  = (const float*)d_in[6];
    const float* wcb  = (const float*)d_in[7];
    const float* ampc = (const float*)d_in[8];
    const float* qw1  = (const float*)d_in[9];
    const float* qb1  = (const float*)d_in[10];
    const float* qw2  = (const float*)d_in[11];
    const float* qb2  = (const float*)d_in[12];
    const float* lng  = (const float*)d_in[13];
    const float* lnb  = (const float*)d_in[14];
    const float* hams = (const float*)d_in[15];
    const float* iw1  = (const float*)d_in[16];
    const float* ib1  = (const float*)d_in[17];
    const float* iw2  = (const float*)d_in[18];
    const float* ib2  = (const float*)d_in[19];
    const float* istr = (const float*)d_in[20];

    char* wsb = (char*)d_ws;
    ushort_t* AHi = (ushort_t*)(wsb + 0);           // q1 hi (dead after s4e)
    ushort_t* ALo = (ushort_t*)(wsb + 33554432);    // q1 lo
    ushort_t* Bwcf = (ushort_t*)(wsb + 67108864);   // wcf single plane (67MB)
    unsigned* psi = (unsigned*)(wsb + 67108864);    // overlays wcf (dead by s4e), 134MB
    float*    msum8 = (float*)(wsb + 0);            // overlays q1 (dead after s4e)
    float*    U    = (float*)(wsb + 201326592);
    float*    sa   = (float*)(wsb + 201392128);
    ushort_t* wb   = (ushort_t*)(wsb + 203489792);
    ushort_t *pw2hi = wb,          *pw2lo = wb + 32768;
    ushort_t *wcwhi = wb + 65536,  *wcwlo = wb + 73728;
    ushort_t *qw1hi = wb + 81920,  *qw1lo = wb + 90112;
    ushort_t *qw2hi = wb + 98304,  *qw2lo = wb + 131072;
    float* out = (float*)d_out;

    k1_expm<<<4, 256, 0, stream>>>(hams, U);
    split_all<<<320, 256, 0, stream>>>(pw2, wcw, qw1, qw2, wb);

    // stage1 (fused h1): x -> wcf (single bf16 plane)
    gemm_s1<<<2048, 256, 0, stream>>>(pw2hi, pw2lo, pb2, x, pw1, pb1,
                                      freq, ampc, Bwcf);
    // stage2+3 fused: wcf -> wf -> q1 (hi/lo)
    s23_v2<<<2048, 256, 0, stream>>>(Bwcf, wcwhi, wcwlo, wcb,
        qw1hi, qw1lo, qb1, AHi, ALo);
    // stage4 + evolve fused: q1 -> LN -> U@psi -> psi packed u32
    gemm_s4e<<<4096, 256, 0, stream>>>(AHi, ALo, qw2hi, qw2lo, qb2,
        lng, lnb, U, psi);

    k3b_fft<<<dim3(32, 4, 8), 256, 0, stream>>>(psi, msum8);
    k4_softdot<<<128, 256, 0, stream>>>(msum8, sa);
    k5_head<<<1, 64, 0, stream>>>(sa, iw1, ib1, iw2, ib2, istr, out);
}